// Round 9
// baseline (56.560 us; speedup 1.0000x reference)
//
#include <hip/hip_runtime.h>
#include <hip/hip_bf16.h>

#define NB      16          // nodes per wave-tile
#define THREADS 256         // 4 independent waves per block

// d_ws layout (float offsets)
#define WS_CST4   0         // 64 x float4 (a*g, b*g, c*g, bet)
#define WS_QUAD   256       // 6 floats: E[a2],E[b2],E[ab],E[ac],E[bc],E[c2]+eps
#define WS_DISC   272       // 18*128 floats: b2 + Ei[a]+Et[b]+Etc[c]
#define WS_W2     2576      // 16 frags * 64 lanes * 16B (bf16 B-fragments)

typedef float f32x4  __attribute__((ext_vector_type(4)));
typedef short bf16x8 __attribute__((ext_vector_type(8)));

static __device__ __forceinline__ unsigned f2bf(float f) {
    __hip_bfloat16 h = __float2bfloat16(f);   // RNE
    return (unsigned)__builtin_bit_cast(unsigned short, h);
}

__global__ __launch_bounds__(THREADS)
void lane_setup_kernel(const float* __restrict__ W1, const float* __restrict__ b1,
                       const float* __restrict__ gam, const float* __restrict__ bet,
                       const float* __restrict__ W2, const float* __restrict__ b2,
                       const float* __restrict__ Ei, const float* __restrict__ Et,
                       const float* __restrict__ Etc, float* __restrict__ ws)
{
    const int tid = threadIdx.x, lane = tid & 63, wv = tid >> 6;

    if (wv == 0) {
        float wx = W1[lane], wy = W1[64 + lane], bb = b1[lane];
        float sx = wx, sy = wy, sb = bb;
        #pragma unroll
        for (int m = 1; m < 64; m <<= 1) {
            sx += __shfl_xor(sx, m, 64);
            sy += __shfl_xor(sy, m, 64);
            sb += __shfl_xor(sb, m, 64);
        }
        float a = wx - sx * (1.f / 64.f);
        float b = wy - sy * (1.f / 64.f);
        float c = bb - sb * (1.f / 64.f);
        float p0 = a * a, p1 = b * b, p2 = a * b, p3 = a * c, p4 = b * c, p5 = c * c;
        #pragma unroll
        for (int m = 1; m < 64; m <<= 1) {
            p0 += __shfl_xor(p0, m, 64); p1 += __shfl_xor(p1, m, 64);
            p2 += __shfl_xor(p2, m, 64); p3 += __shfl_xor(p3, m, 64);
            p4 += __shfl_xor(p4, m, 64); p5 += __shfl_xor(p5, m, 64);
        }
        float g = gam[lane];
        ((float4*)(ws + WS_CST4))[lane] = make_float4(a * g, b * g, c * g, bet[lane]);
        if (lane == 0) {
            ws[WS_QUAD + 0] = p0 * (1.f / 64.f);
            ws[WS_QUAD + 1] = p1 * (1.f / 64.f);
            ws[WS_QUAD + 2] = p2 * (1.f / 64.f);
            ws[WS_QUAD + 3] = p3 * (1.f / 64.f);
            ws[WS_QUAD + 4] = p4 * (1.f / 64.f);
            ws[WS_QUAD + 5] = p5 * (1.f / 64.f) + 1e-5f;   // fold LN eps
        }
    }

    // W2 bf16 fragments, exact per-lane MFMA-B layout
    {
        uint4* dst = (uint4*)(ws + WS_W2);
        #pragma unroll
        for (int f = wv * 4; f < wv * 4 + 4; ++f) {
            int c = f >> 1, kt = f & 1;
            int col = c * 16 + (lane & 15);
            int k0  = kt * 32 + (lane >> 4) * 8;
            unsigned w[4];
            #pragma unroll
            for (int j = 0; j < 4; ++j) {
                unsigned lo = f2bf(W2[(k0 + 2 * j) * 128 + col]);
                unsigned hi = f2bf(W2[(k0 + 2 * j + 1) * 128 + col]);
                w[j] = (hi << 16) | lo;
            }
            dst[f * 64 + lane] = make_uint4(w[0], w[1], w[2], w[3]);
        }
    }

    // disc table: all 18 (a,b,c) combos, b2 folded in
    for (int i = tid; i < 18 * 128; i += THREADS) {
        int combo = i >> 7, col = i & 127;
        int ai = combo / 6; int r = combo - ai * 6; int bi = r >> 1; int ci = r & 1;
        ws[WS_DISC + i] = b2[col] + Ei[ai * 128 + col] + Et[bi * 128 + col] + Etc[ci * 128 + col];
    }
}

__global__ __launch_bounds__(THREADS)
__attribute__((amdgpu_waves_per_eu(4, 4)))   // pin: exactly 4 waves/EU -> 128-VGPR budget
void lane_node_embed_mfma(const float* __restrict__ pos,      // [N,10,2]
                          const int*   __restrict__ idx_int,  // [N]
                          const int*   __restrict__ idx_turn, // [N]
                          const int*   __restrict__ idx_tc,   // [N]
                          const float* __restrict__ ws,
                          float* __restrict__ out,            // [N,128]
                          int n_nodes)
{
    const int tid  = threadIdx.x;
    const int lane = tid & 63;
    const int wv   = tid >> 6;
    const int tile = blockIdx.x * 4 + wv;     // one wave = one 16-node tile
    const int base = tile * NB;

    const int l15 = lane & 15;
    const int g   = lane >> 4;

    // combo index for node l15 — issue early, consumed in epilogue
    const int gn15 = base + l15;
    int cmb = 0;
    if (gn15 < n_nodes)
        cmb = (idx_int[gn15] * 3 + idx_turn[gn15]) * 2 + idx_tc[gn15];

    // LN quadratic constants (wave-uniform -> s_loads)
    const float qA = ws[WS_QUAD + 0], qB = ws[WS_QUAD + 1], qC = ws[WS_QUAD + 2];
    const float qD = ws[WS_QUAD + 3], qE = ws[WS_QUAD + 4], qF = ws[WS_QUAD + 5];

    // ---- stash (ax, ay) for all 144 (node,p): slot s -> lane (g,l15) owns
    // (node=l15, p=s*4+g); p>=9 lanes idle
    float axs[3], ays[3];
    #pragma unroll
    for (int s = 0; s < 3; ++s) {
        int p = s * 4 + g;
        float ax = 0.f, ay = 0.f;
        int gn = base + l15;
        if (p < 9 && gn < n_nodes) {
            const float2* pp = (const float2*)pos + (size_t)gn * 10 + p;
            float2 q0 = pp[0], q1 = pp[1];
            float dx = q1.x - q0.x, dy = q1.y - q0.y;
            float inv = rsqrtf(fmaf(dx, dx, fmaf(dy, dy, 1e-6f)));
            dx *= inv; dy *= inv;
            float tt  = fmaf(dx * dy, qC, fmaf(dx, qD, dy * qE));
            float var = fmaf(2.f, tt, fmaf(dx * dx, qA, fmaf(dy * dy, qB, qF)));
            float is0 = rsqrtf(var);
            ax = dx * is0; ay = dy * is0;
        }
        axs[s] = ax; ays[s] = ay;
    }

    const float4* c4p = (const float4*)(ws + WS_CST4);

    // ---- build A-fragments for all 9 p, one kt-half at a time ----
    bf16x8 A0[9], A1[9];
    #pragma unroll
    for (int kt = 0; kt < 2; ++kt) {
        float4 cst[8];
        #pragma unroll
        for (int j = 0; j < 8; ++j) cst[j] = c4p[kt * 32 + g * 8 + j];

        #pragma unroll
        for (int p = 0; p < 9; ++p) {
            const int s = p >> 2;                  // compile-time slot
            const int o = ((p & 3) << 4) | l15;    // owner lane of (node=l15, p)
            float ax = __shfl(axs[s], o, 64);
            float ay = __shfl(ays[s], o, 64);
            float is = sqrtf(fmaf(ax, ax, ay * ay));   // exact: (dx,dy) normalized

            unsigned w[4];
            #pragma unroll
            for (int j = 0; j < 4; ++j) {
                float4 cA = cst[2 * j], cB = cst[2 * j + 1];
                float a = fmaxf(fmaf(ax, cA.x, fmaf(ay, cA.y, fmaf(is, cA.z, cA.w))), 0.f);
                float b = fmaxf(fmaf(ax, cB.x, fmaf(ay, cB.y, fmaf(is, cB.z, cB.w))), 0.f);
                w[j] = (f2bf(b) << 16) | f2bf(a);
            }
            bf16x8 fr = __builtin_bit_cast(bf16x8, make_uint4(w[0], w[1], w[2], w[3]));
            if (kt == 0) A0[p] = fr; else A1[p] = fr;
        }
    }

    // per-node combos for this lane's 4 output nodes
    int cj[4];
    #pragma unroll
    for (int jj = 0; jj < 4; ++jj) cj[jj] = __shfl(cmb, g * 4 + jj, 64);

    // ---- phase B: stream B-coltiles in 4 groups of 2; acc transient ----
    const uint4* wfr = (const uint4*)(ws + WS_W2);
    const f32x4 zz = {0.f, 0.f, 0.f, 0.f};

    #pragma unroll
    for (int cg = 0; cg < 4; ++cg) {
        bf16x8 B[2][2];
        #pragma unroll
        for (int c = 0; c < 2; ++c)
            #pragma unroll
            for (int kt = 0; kt < 2; ++kt)
                B[c][kt] = __builtin_bit_cast(bf16x8,
                               wfr[((cg * 2 + c) * 2 + kt) * 64 + lane]);

        #pragma unroll
        for (int c = 0; c < 2; ++c) {
            f32x4 mx = {-INFINITY, -INFINITY, -INFINITY, -INFINITY};
            #pragma unroll
            for (int p = 0; p < 9; ++p) {
                f32x4 t = __builtin_amdgcn_mfma_f32_16x16x32_bf16(A0[p], B[c][0], zz, 0, 0, 0);
                t       = __builtin_amdgcn_mfma_f32_16x16x32_bf16(A1[p], B[c][1], t,  0, 0, 0);
                #pragma unroll
                for (int k = 0; k < 4; ++k) mx[k] = fmaxf(mx[k], t[k]);
            }
            const int col = (cg * 2 + c) * 16 + l15;
            #pragma unroll
            for (int jj = 0; jj < 4; ++jj) {
                int gnj = base + g * 4 + jj;
                if (gnj < n_nodes)
                    out[(size_t)gnj * 128 + col] = mx[jj] + ws[WS_DISC + cj[jj] * 128 + col];
            }
        }
    }
}

extern "C" void kernel_launch(void* const* d_in, const int* in_sizes, int n_in,
                              void* d_out, int out_size, void* d_ws, size_t ws_size,
                              hipStream_t stream) {
    const float* pos  = (const float*)d_in[0];
    const int*   ii   = (const int*)  d_in[1];
    const int*   it   = (const int*)  d_in[2];
    const int*   itc  = (const int*)  d_in[3];
    const float* W1   = (const float*)d_in[4];
    const float* b1   = (const float*)d_in[5];
    const float* gam  = (const float*)d_in[6];
    const float* bet  = (const float*)d_in[7];
    const float* W2   = (const float*)d_in[8];
    const float* b2   = (const float*)d_in[9];
    const float* Ei   = (const float*)d_in[10];
    const float* Et   = (const float*)d_in[11];
    const float* Etc  = (const float*)d_in[12];
    float* out = (float*)d_out;
    float* ws  = (float*)d_ws;

    int n_nodes = in_sizes[1];                              // B*L = 65536
    int tiles   = (n_nodes + NB - 1) / NB;                  // 4096
    int blocks  = (tiles + 3) / 4;                          // 1024 (4 waves/block)

    hipLaunchKernelGGL(lane_setup_kernel, dim3(1), dim3(THREADS), 0, stream,
                       W1, b1, gam, bet, W2, b2, Ei, Et, Etc, ws);
    hipLaunchKernelGGL(lane_node_embed_mfma, dim3(blocks), dim3(THREADS), 0, stream,
                       pos, ii, it, itc, ws, out, n_nodes);
}

// Round 10
// 37.279 us; speedup vs baseline: 1.5172x; 1.5172x over previous
//
#include <hip/hip_runtime.h>
#include <hip/hip_bf16.h>

#define NB      16          // nodes per wave-tile
#define THREADS 256         // 4 independent waves per block

// d_ws layout (float offsets)
#define WS_CST4   0         // 64 x float4 (a*g, b*g, c*g, bet)
#define WS_QUAD   256       // 6 floats: E[a2],E[b2],E[ab],E[ac],E[bc],E[c2]+eps
#define WS_DISC   272       // 18*128 floats: b2 + Ei[a]+Et[b]+Etc[c]
#define WS_W2     2576      // 16 frags * 64 lanes * 16B (bf16 B-fragments)

typedef float f32x4  __attribute__((ext_vector_type(4)));
typedef short bf16x8 __attribute__((ext_vector_type(8)));

static __device__ __forceinline__ unsigned f2bf(float f) {
    __hip_bfloat16 h = __float2bfloat16(f);   // RNE
    return (unsigned)__builtin_bit_cast(unsigned short, h);
}

__global__ __launch_bounds__(THREADS)
void lane_setup_kernel(const float* __restrict__ W1, const float* __restrict__ b1,
                       const float* __restrict__ gam, const float* __restrict__ bet,
                       const float* __restrict__ W2, const float* __restrict__ b2,
                       const float* __restrict__ Ei, const float* __restrict__ Et,
                       const float* __restrict__ Etc, float* __restrict__ ws)
{
    const int tid = threadIdx.x, lane = tid & 63, wv = tid >> 6;

    if (wv == 0) {
        float wx = W1[lane], wy = W1[64 + lane], bb = b1[lane];
        float sx = wx, sy = wy, sb = bb;
        #pragma unroll
        for (int m = 1; m < 64; m <<= 1) {
            sx += __shfl_xor(sx, m, 64);
            sy += __shfl_xor(sy, m, 64);
            sb += __shfl_xor(sb, m, 64);
        }
        float a = wx - sx * (1.f / 64.f);
        float b = wy - sy * (1.f / 64.f);
        float c = bb - sb * (1.f / 64.f);
        float p0 = a * a, p1 = b * b, p2 = a * b, p3 = a * c, p4 = b * c, p5 = c * c;
        #pragma unroll
        for (int m = 1; m < 64; m <<= 1) {
            p0 += __shfl_xor(p0, m, 64); p1 += __shfl_xor(p1, m, 64);
            p2 += __shfl_xor(p2, m, 64); p3 += __shfl_xor(p3, m, 64);
            p4 += __shfl_xor(p4, m, 64); p5 += __shfl_xor(p5, m, 64);
        }
        float g = gam[lane];
        ((float4*)(ws + WS_CST4))[lane] = make_float4(a * g, b * g, c * g, bet[lane]);
        if (lane == 0) {
            ws[WS_QUAD + 0] = p0 * (1.f / 64.f);
            ws[WS_QUAD + 1] = p1 * (1.f / 64.f);
            ws[WS_QUAD + 2] = p2 * (1.f / 64.f);
            ws[WS_QUAD + 3] = p3 * (1.f / 64.f);
            ws[WS_QUAD + 4] = p4 * (1.f / 64.f);
            ws[WS_QUAD + 5] = p5 * (1.f / 64.f) + 1e-5f;   // fold LN eps
        }
    }

    // W2 bf16 fragments, exact per-lane MFMA-B layout
    {
        uint4* dst = (uint4*)(ws + WS_W2);
        #pragma unroll
        for (int f = wv * 4; f < wv * 4 + 4; ++f) {
            int c = f >> 1, kt = f & 1;
            int col = c * 16 + (lane & 15);
            int k0  = kt * 32 + (lane >> 4) * 8;
            unsigned w[4];
            #pragma unroll
            for (int j = 0; j < 4; ++j) {
                unsigned lo = f2bf(W2[(k0 + 2 * j) * 128 + col]);
                unsigned hi = f2bf(W2[(k0 + 2 * j + 1) * 128 + col]);
                w[j] = (hi << 16) | lo;
            }
            dst[f * 64 + lane] = make_uint4(w[0], w[1], w[2], w[3]);
        }
    }

    // disc table: all 18 (a,b,c) combos, b2 folded in
    for (int i = tid; i < 18 * 128; i += THREADS) {
        int combo = i >> 7, col = i & 127;
        int ai = combo / 6; int r = combo - ai * 6; int bi = r >> 1; int ci = r & 1;
        ws[WS_DISC + i] = b2[col] + Ei[ai * 128 + col] + Et[bi * 128 + col] + Etc[ci * 128 + col];
    }
}

__global__ __launch_bounds__(THREADS)   // NO occupancy attr: allocator uses true need
void lane_node_embed_mfma(const float* __restrict__ pos,      // [N,10,2]
                          const int*   __restrict__ idx_int,  // [N]
                          const int*   __restrict__ idx_turn, // [N]
                          const int*   __restrict__ idx_tc,   // [N]
                          const float* __restrict__ ws,
                          float* __restrict__ out,            // [N,128]
                          int n_nodes)
{
    const int tid  = threadIdx.x;
    const int lane = tid & 63;
    const int wv   = tid >> 6;
    const int tile = blockIdx.x * 4 + wv;     // one wave = one 16-node tile
    const int base = tile * NB;

    const int l15 = lane & 15;
    const int g   = lane >> 4;

    // combo index for node l15 — issue early, consumed in epilogue
    const int gn15 = base + l15;
    int cmb = 0;
    if (gn15 < n_nodes)
        cmb = (idx_int[gn15] * 3 + idx_turn[gn15]) * 2 + idx_tc[gn15];

    // LN quadratic constants (wave-uniform -> s_loads)
    const float qA = ws[WS_QUAD + 0], qB = ws[WS_QUAD + 1], qC = ws[WS_QUAD + 2];
    const float qD = ws[WS_QUAD + 3], qE = ws[WS_QUAD + 4], qF = ws[WS_QUAD + 5];

    // ---- stash (ax, ay) for all 144 (node,p): slot s -> lane (g,l15) owns
    // (node=l15, p=s*4+g); p>=9 lanes idle
    float axs[3], ays[3];
    #pragma unroll
    for (int s = 0; s < 3; ++s) {
        int p = s * 4 + g;
        float ax = 0.f, ay = 0.f;
        int gn = base + l15;
        if (p < 9 && gn < n_nodes) {
            const float2* pp = (const float2*)pos + (size_t)gn * 10 + p;
            float2 q0 = pp[0], q1 = pp[1];
            float dx = q1.x - q0.x, dy = q1.y - q0.y;
            float inv = rsqrtf(fmaf(dx, dx, fmaf(dy, dy, 1e-6f)));
            dx *= inv; dy *= inv;
            float tt  = fmaf(dx * dy, qC, fmaf(dx, qD, dy * qE));
            float var = fmaf(2.f, tt, fmaf(dx * dx, qA, fmaf(dy * dy, qB, qF)));
            float is0 = rsqrtf(var);
            ax = dx * is0; ay = dy * is0;
        }
        axs[s] = ax; ays[s] = ay;
    }

    const float4* c4p = (const float4*)(ws + WS_CST4);

    // ---- build A-fragment words; cst streamed as 4-float4 quarter-tables ----
    unsigned aw[2][9][4];                      // 72 VGPR, all indices compile-time
    #pragma unroll
    for (int kt = 0; kt < 2; ++kt) {
        #pragma unroll
        for (int jh = 0; jh < 2; ++jh) {
            float4 cq[4];                      // 16 VGPR, transient
            #pragma unroll
            for (int q = 0; q < 4; ++q)
                cq[q] = c4p[kt * 32 + g * 8 + jh * 4 + q];

            #pragma unroll
            for (int p = 0; p < 9; ++p) {
                const int s = p >> 2;                  // compile-time slot
                const int o = ((p & 3) << 4) | l15;    // owner lane of (node=l15, p)
                float ax = __shfl(axs[s], o, 64);
                float ay = __shfl(ays[s], o, 64);
                float is = sqrtf(fmaf(ax, ax, ay * ay));   // exact: (dx,dy) normalized

                #pragma unroll
                for (int jj = 0; jj < 2; ++jj) {
                    float4 cA = cq[2 * jj], cB = cq[2 * jj + 1];
                    float a = fmaxf(fmaf(ax, cA.x, fmaf(ay, cA.y, fmaf(is, cA.z, cA.w))), 0.f);
                    float b = fmaxf(fmaf(ax, cB.x, fmaf(ay, cB.y, fmaf(is, cB.z, cB.w))), 0.f);
                    aw[kt][p][jh * 2 + jj] = (f2bf(b) << 16) | f2bf(a);
                }
            }
        }
    }

    // per-node combos for this lane's 4 output nodes
    int cj[4];
    #pragma unroll
    for (int jj = 0; jj < 4; ++jj) cj[jj] = __shfl(cmb, g * 4 + jj, 64);

    // ---- phase B: stream B-coltiles in 4 groups of 2; acc transient ----
    const uint4* wfr = (const uint4*)(ws + WS_W2);
    const f32x4 zz = {0.f, 0.f, 0.f, 0.f};

    #pragma unroll
    for (int cg = 0; cg < 4; ++cg) {
        bf16x8 B[2][2];
        #pragma unroll
        for (int c = 0; c < 2; ++c)
            #pragma unroll
            for (int kt = 0; kt < 2; ++kt)
                B[c][kt] = __builtin_bit_cast(bf16x8,
                               wfr[((cg * 2 + c) * 2 + kt) * 64 + lane]);

        #pragma unroll
        for (int c = 0; c < 2; ++c) {
            f32x4 mx = {-INFINITY, -INFINITY, -INFINITY, -INFINITY};
            #pragma unroll
            for (int p = 0; p < 9; ++p) {
                bf16x8 a0 = __builtin_bit_cast(bf16x8,
                    make_uint4(aw[0][p][0], aw[0][p][1], aw[0][p][2], aw[0][p][3]));
                bf16x8 a1 = __builtin_bit_cast(bf16x8,
                    make_uint4(aw[1][p][0], aw[1][p][1], aw[1][p][2], aw[1][p][3]));
                f32x4 t = __builtin_amdgcn_mfma_f32_16x16x32_bf16(a0, B[c][0], zz, 0, 0, 0);
                t       = __builtin_amdgcn_mfma_f32_16x16x32_bf16(a1, B[c][1], t,  0, 0, 0);
                #pragma unroll
                for (int k = 0; k < 4; ++k) mx[k] = fmaxf(mx[k], t[k]);
            }
            const int col = (cg * 2 + c) * 16 + l15;
            #pragma unroll
            for (int jj = 0; jj < 4; ++jj) {
                int gnj = base + g * 4 + jj;
                if (gnj < n_nodes)
                    out[(size_t)gnj * 128 + col] = mx[jj] + ws[WS_DISC + cj[jj] * 128 + col];
            }
        }
    }
}

extern "C" void kernel_launch(void* const* d_in, const int* in_sizes, int n_in,
                              void* d_out, int out_size, void* d_ws, size_t ws_size,
                              hipStream_t stream) {
    const float* pos  = (const float*)d_in[0];
    const int*   ii   = (const int*)  d_in[1];
    const int*   it   = (const int*)  d_in[2];
    const int*   itc  = (const int*)  d_in[3];
    const float* W1   = (const float*)d_in[4];
    const float* b1   = (const float*)d_in[5];
    const float* gam  = (const float*)d_in[6];
    const float* bet  = (const float*)d_in[7];
    const float* W2   = (const float*)d_in[8];
    const float* b2   = (const float*)d_in[9];
    const float* Ei   = (const float*)d_in[10];
    const float* Et   = (const float*)d_in[11];
    const float* Etc  = (const float*)d_in[12];
    float* out = (float*)d_out;
    float* ws  = (float*)d_ws;

    int n_nodes = in_sizes[1];                              // B*L = 65536
    int tiles   = (n_nodes + NB - 1) / NB;                  // 4096
    int blocks  = (tiles + 3) / 4;                          // 1024 (4 waves/block)

    hipLaunchKernelGGL(lane_setup_kernel, dim3(1), dim3(THREADS), 0, stream,
                       W1, b1, gam, bet, W2, b2, Ei, Et, Etc, ws);
    hipLaunchKernelGGL(lane_node_embed_mfma, dim3(blocks), dim3(THREADS), 0, stream,
                       pos, ii, it, itc, ws, out, n_nodes);
}

// Round 11
// 30.448 us; speedup vs baseline: 1.8576x; 1.2243x over previous
//
#include <hip/hip_runtime.h>
#include <hip/hip_bf16.h>

#define NB      16          // nodes per block (one MFMA M-tile)
#define THREADS 256

// d_ws layout (float offsets)
#define WS_CST4   0         // 64 x float4 (a*g, b*g, c*g, bet)
#define WS_QUAD   256       // 6 floats: E[a2],E[b2],E[ab],E[ac],E[bc],E[c2]+eps
#define WS_DISC   272       // 18*128 floats: b2 + Ei[a]+Et[b]+Etc[c]
#define WS_W2     2576      // 16 frags * 64 lanes * 16B (bf16 B-fragments)

typedef float f32x4  __attribute__((ext_vector_type(4)));
typedef short bf16x8 __attribute__((ext_vector_type(8)));

static __device__ __forceinline__ unsigned f2bf(float f) {
    __hip_bfloat16 h = __float2bfloat16(f);   // RNE
    return (unsigned)__builtin_bit_cast(unsigned short, h);
}

__global__ __launch_bounds__(THREADS)
void lane_setup_kernel(const float* __restrict__ W1, const float* __restrict__ b1,
                       const float* __restrict__ gam, const float* __restrict__ bet,
                       const float* __restrict__ W2, const float* __restrict__ b2,
                       const float* __restrict__ Ei, const float* __restrict__ Et,
                       const float* __restrict__ Etc, float* __restrict__ ws)
{
    const int tid = threadIdx.x, lane = tid & 63, wv = tid >> 6;

    if (wv == 0) {
        float wx = W1[lane], wy = W1[64 + lane], bb = b1[lane];
        float sx = wx, sy = wy, sb = bb;
        #pragma unroll
        for (int m = 1; m < 64; m <<= 1) {
            sx += __shfl_xor(sx, m, 64);
            sy += __shfl_xor(sy, m, 64);
            sb += __shfl_xor(sb, m, 64);
        }
        float a = wx - sx * (1.f / 64.f);
        float b = wy - sy * (1.f / 64.f);
        float c = bb - sb * (1.f / 64.f);
        float p0 = a * a, p1 = b * b, p2 = a * b, p3 = a * c, p4 = b * c, p5 = c * c;
        #pragma unroll
        for (int m = 1; m < 64; m <<= 1) {
            p0 += __shfl_xor(p0, m, 64); p1 += __shfl_xor(p1, m, 64);
            p2 += __shfl_xor(p2, m, 64); p3 += __shfl_xor(p3, m, 64);
            p4 += __shfl_xor(p4, m, 64); p5 += __shfl_xor(p5, m, 64);
        }
        float g = gam[lane];
        ((float4*)(ws + WS_CST4))[lane] = make_float4(a * g, b * g, c * g, bet[lane]);
        if (lane == 0) {
            ws[WS_QUAD + 0] = p0 * (1.f / 64.f);
            ws[WS_QUAD + 1] = p1 * (1.f / 64.f);
            ws[WS_QUAD + 2] = p2 * (1.f / 64.f);
            ws[WS_QUAD + 3] = p3 * (1.f / 64.f);
            ws[WS_QUAD + 4] = p4 * (1.f / 64.f);
            ws[WS_QUAD + 5] = p5 * (1.f / 64.f) + 1e-5f;   // fold LN eps
        }
    }

    // W2 bf16 fragments, exact per-lane MFMA-B layout
    {
        uint4* dst = (uint4*)(ws + WS_W2);
        #pragma unroll
        for (int f = wv * 4; f < wv * 4 + 4; ++f) {
            int c = f >> 1, kt = f & 1;
            int col = c * 16 + (lane & 15);
            int k0  = kt * 32 + (lane >> 4) * 8;
            unsigned w[4];
            #pragma unroll
            for (int j = 0; j < 4; ++j) {
                unsigned lo = f2bf(W2[(k0 + 2 * j) * 128 + col]);
                unsigned hi = f2bf(W2[(k0 + 2 * j + 1) * 128 + col]);
                w[j] = (hi << 16) | lo;
            }
            dst[f * 64 + lane] = make_uint4(w[0], w[1], w[2], w[3]);
        }
    }

    // disc table: all 18 (a,b,c) combos, b2 folded in
    for (int i = tid; i < 18 * 128; i += THREADS) {
        int combo = i >> 7, col = i & 127;
        int ai = combo / 6; int r = combo - ai * 6; int bi = r >> 1; int ci = r & 1;
        ws[WS_DISC + i] = b2[col] + Ei[ai * 128 + col] + Et[bi * 128 + col] + Etc[ci * 128 + col];
    }
}

__global__ __launch_bounds__(THREADS)
void lane_node_embed_mfma(const float* __restrict__ pos,      // [N,10,2]
                          const int*   __restrict__ idx_int,  // [N]
                          const int*   __restrict__ idx_turn, // [N]
                          const int*   __restrict__ idx_tc,   // [N]
                          const float* __restrict__ ws,
                          float* __restrict__ out,            // [N,128]
                          int n_nodes)
{
    // H[node][p][64 bf16], 16B-chunk swizzle: chunk' = chunk ^ (node&7)
    __shared__ __align__(16) unsigned short H[NB * 9 * 64];   // 18 KB
    __shared__ float4 smv[NB * 9];              // per-row (ax, ay, is, 0)
    __shared__ int    cmb_lds[NB];

    const int tid  = threadIdx.x;
    const int lane = tid & 63;
    const int wv   = __builtin_amdgcn_readfirstlane(tid >> 6);
    const int blockStart = blockIdx.x * NB;

    // ---- stash first: cold pos loads issue before everything else ----
    if (tid < NB * 9) {
        int nd = tid / 9, p = tid - nd * 9;
        int gn = blockStart + nd;
        float ax = 0.f, ay = 0.f, is = 0.f;
        if (gn < n_nodes) {
            const float2* pp = (const float2*)pos + (size_t)gn * 10 + p;
            float2 q0 = pp[0], q1 = pp[1];
            float dx = q1.x - q0.x, dy = q1.y - q0.y;
            float inv = rsqrtf(fmaf(dx, dx, fmaf(dy, dy, 1e-6f)));
            dx *= inv; dy *= inv;
            float qA = ws[WS_QUAD + 0], qB = ws[WS_QUAD + 1], qC = ws[WS_QUAD + 2];
            float qD = ws[WS_QUAD + 3], qE = ws[WS_QUAD + 4], qF = ws[WS_QUAD + 5];
            float t   = fmaf(dx * dy, qC, fmaf(dx, qD, dy * qE));
            float var = fmaf(2.f, t, fmaf(dx * dx, qA, fmaf(dy * dy, qB, qF)));
            is = rsqrtf(var);
            ax = dx * is; ay = dy * is;
        }
        smv[tid] = make_float4(ax, ay, is, 0.f);
    }
    if (tid < NB) {
        int gn = blockStart + tid;
        cmb_lds[tid] = (gn < n_nodes)
            ? (idx_int[gn] * 3 + idx_turn[gn]) * 2 + idx_tc[gn] : 0;
    }

    // per-lane LN constants for this lane's k-pair (2*kl, 2*kl+1)
    const int kl   = lane & 31;
    const int half = lane >> 5;
    const float4 cstA = ((const float4*)(ws + WS_CST4))[2 * kl];
    const float4 cstB = ((const float4*)(ws + WS_CST4))[2 * kl + 1];

    // B fragments for this wave's 2 coltiles (prepacked, coalesced)
    const int ct0 = wv * 2;
    const uint4* wfr = (const uint4*)(ws + WS_W2);
    bf16x8 Bfr[2][2];
    #pragma unroll
    for (int c = 0; c < 2; ++c)
        #pragma unroll
        for (int kt = 0; kt < 2; ++kt)
            Bfr[c][kt] = __builtin_bit_cast(bf16x8, wfr[((ct0 + c) * 2 + kt) * 64 + lane]);

    __syncthreads();

    // ---- Phase A (k-pair): halves handle 2 nodes/iter, packed b32 writes ----
    {
        const int kch  = kl >> 2;            // 16B chunk of k0=2*kl
        const int kofs = (2 * kl) & 7;       // ushort offset within chunk
        #pragma unroll
        for (int i = 0; i < 2; ++i) {
            int nd = wv * 4 + 2 * i + half;
            int basew = nd * 576 + ((kch ^ (nd & 7)) << 3) + kofs;
            #pragma unroll
            for (int p = 0; p < 9; ++p) {
                float4 t = smv[nd * 9 + p];          // broadcast read per half
                float a = fmaf(t.x, cstA.x, fmaf(t.y, cstA.y, fmaf(t.z, cstA.z, cstA.w)));
                float b = fmaf(t.x, cstB.x, fmaf(t.y, cstB.y, fmaf(t.z, cstB.z, cstB.w)));
                a = fmaxf(a, 0.f); b = fmaxf(b, 0.f);
                *(unsigned*)&H[basew + p * 64] = (f2bf(b) << 16) | f2bf(a);
            }
        }
    }
    __syncthreads();

    // ---- Phase B: M-rows = 16 nodes; max over p via VALU between MFMAs ----
    const int g   = lane >> 4;
    const int l15 = lane & 15;
    const int sr  = l15 & 7;
    const int i0  = l15 * 576 + ((g ^ sr) << 3);          // kt=0 chunk
    const int i1  = l15 * 576 + (((4 + g) ^ sr) << 3);    // kt=1 chunk

    // prefetch disc values: loads fly under the MFMA loop
    int cjv[4];
    #pragma unroll
    for (int jj = 0; jj < 4; ++jj) cjv[jj] = cmb_lds[g * 4 + jj];
    float dvp[2][4];
    #pragma unroll
    for (int c = 0; c < 2; ++c)
        #pragma unroll
        for (int jj = 0; jj < 4; ++jj)
            dvp[c][jj] = ws[WS_DISC + cjv[jj] * 128 + (ct0 + c) * 16 + l15];

    f32x4 mx0 = {-INFINITY, -INFINITY, -INFINITY, -INFINITY};
    f32x4 mx1 = mx0;
    const f32x4 zz = {0.f, 0.f, 0.f, 0.f};
    #pragma unroll
    for (int p = 0; p < 9; ++p) {
        bf16x8 a0 = *(const bf16x8*)&H[i0 + p * 64];
        bf16x8 a1 = *(const bf16x8*)&H[i1 + p * 64];
        f32x4 t0 = __builtin_amdgcn_mfma_f32_16x16x32_bf16(a0, Bfr[0][0], zz, 0, 0, 0);
        t0       = __builtin_amdgcn_mfma_f32_16x16x32_bf16(a1, Bfr[0][1], t0, 0, 0, 0);
        f32x4 t1 = __builtin_amdgcn_mfma_f32_16x16x32_bf16(a0, Bfr[1][0], zz, 0, 0, 0);
        t1       = __builtin_amdgcn_mfma_f32_16x16x32_bf16(a1, Bfr[1][1], t1, 0, 0, 0);
        #pragma unroll
        for (int k = 0; k < 4; ++k) {
            mx0[k] = fmaxf(mx0[k], t0[k]);
            mx1[k] = fmaxf(mx1[k], t1[k]);
        }
    }

    // ---- epilogue: pure add + store (disc already in regs) ----
    #pragma unroll
    for (int c = 0; c < 2; ++c) {
        int col = (ct0 + c) * 16 + l15;
        f32x4 m = (c == 0) ? mx0 : mx1;
        #pragma unroll
        for (int j = 0; j < 4; ++j) {
            int gn = blockStart + g * 4 + j;
            if (gn < n_nodes)
                out[(size_t)gn * 128 + col] = m[j] + dvp[c][j];
        }
    }
}

extern "C" void kernel_launch(void* const* d_in, const int* in_sizes, int n_in,
                              void* d_out, int out_size, void* d_ws, size_t ws_size,
                              hipStream_t stream) {
    const float* pos  = (const float*)d_in[0];
    const int*   ii   = (const int*)  d_in[1];
    const int*   it   = (const int*)  d_in[2];
    const int*   itc  = (const int*)  d_in[3];
    const float* W1   = (const float*)d_in[4];
    const float* b1   = (const float*)d_in[5];
    const float* gam  = (const float*)d_in[6];
    const float* bet  = (const float*)d_in[7];
    const float* W2   = (const float*)d_in[8];
    const float* b2   = (const float*)d_in[9];
    const float* Ei   = (const float*)d_in[10];
    const float* Et   = (const float*)d_in[11];
    const float* Etc  = (const float*)d_in[12];
    float* out = (float*)d_out;
    float* ws  = (float*)d_ws;

    int n_nodes = in_sizes[1];                       // B*L = 65536
    int blocks  = (n_nodes + NB - 1) / NB;           // 4096

    hipLaunchKernelGGL(lane_setup_kernel, dim3(1), dim3(THREADS), 0, stream,
                       W1, b1, gam, bet, W2, b2, Ei, Et, Etc, ws);
    hipLaunchKernelGGL(lane_node_embed_mfma, dim3(blocks), dim3(THREADS), 0, stream,
                       pos, ii, it, itc, ws, out, n_nodes);
}